// Round 12
// baseline (794.224 us; speedup 1.0000x reference)
//
#include <hip/hip_runtime.h>
#include <stdint.h>

#define NB 4
#define NN 8192
#define KNB 30
#define TOT (NB * NN)

// ---------------- threefry2x32 (JAX-exact, key = [0, 42]) ----------------
__device__ __forceinline__ uint32_t rotl32(uint32_t v, int r) {
    return (v << r) | (v >> (32 - r));
}

__device__ __forceinline__ void threefry(uint32_t x0, uint32_t x1,
                                         uint32_t& o0, uint32_t& o1) {
    const uint32_t ks0 = 0u, ks1 = 42u, ks2 = 0u ^ 42u ^ 0x1BD11BDAu;
    x0 += ks0; x1 += ks1;
#define RND(r) { x0 += x1; x1 = rotl32(x1, r); x1 ^= x0; }
    RND(13) RND(15) RND(26) RND(6)
    x0 += ks1; x1 += ks2 + 1u;
    RND(17) RND(29) RND(16) RND(24)
    x0 += ks2; x1 += ks0 + 2u;
    RND(13) RND(15) RND(26) RND(6)
    x0 += ks0; x1 += ks1 + 3u;
    RND(17) RND(29) RND(16) RND(24)
    x0 += ks1; x1 += ks2 + 4u;
    RND(13) RND(15) RND(26) RND(6)
    x0 += ks2; x1 += ks0 + 5u;
#undef RND
    o0 = x0; o1 = x1;
}

// jax_threefry_partitionable=True: bits[t] = o0^o1 of threefry(key, 0, t)
__global__ void init_z_kernel(float* __restrict__ z) {
    int t = blockIdx.x * blockDim.x + threadIdx.x;
    if (t >= TOT) return;
    uint32_t o0, o1;
    threefry(0u, (uint32_t)t, o0, o1);
    uint32_t bits = o0 ^ o1;
    z[t] = __uint_as_float((bits >> 9) | 0x3f800000u) - 1.0f;
}

// ------------- per-batch stable compaction of valid nodes to SoA -------------
// vx/vy/vz[b][m], vidx[b][m] for m < nv[b]; pad to NN with +inf coords.
__global__ __launch_bounds__(256) void compact_kernel(const float* __restrict__ X,
                                                      const int* __restrict__ C,
                                                      float* __restrict__ vx,
                                                      float* __restrict__ vy,
                                                      float* __restrict__ vz,
                                                      int* __restrict__ vidx,
                                                      int* __restrict__ nvarr) {
    const int b = blockIdx.x;
    const int t = threadIdx.x;
    const float* Xb = X + (size_t)b * NN * 3;
    const int* Cb = C + (size_t)b * NN;
    float* vxb = vx + (size_t)b * NN;
    float* vyb = vy + (size_t)b * NN;
    float* vzb = vz + (size_t)b * NN;
    int* vib = vidx + (size_t)b * NN;

    const int base = t * 32;
    uint32_t flags = 0u;
    int cnt = 0;
    for (int q = 0; q < 32; ++q) {
        int v = (Cb[base + q] > 0) ? 1 : 0;
        flags |= (uint32_t)v << q;
        cnt += v;
    }
    // block exclusive scan over 256 per-thread counts
    __shared__ int wsum[4];
    __shared__ int stot;
    int incl = cnt;
    for (int off = 1; off < 64; off <<= 1) {
        int o = __shfl_up(incl, off, 64);
        if ((t & 63) >= off) incl += o;
    }
    if ((t & 63) == 63) wsum[t >> 6] = incl;
    __syncthreads();
    int woff = 0;
    for (int w = 0; w < (t >> 6); ++w) woff += wsum[w];
    const int off0 = woff + incl - cnt;  // exclusive global offset
    if (t == 255) stot = off0 + cnt;     // nv
    int om = off0;
    for (int q = 0; q < 32; ++q) {
        if ((flags >> q) & 1u) {
            const int j = base + q;
            vxb[om] = Xb[j * 3 + 0];
            vyb[om] = Xb[j * 3 + 1];
            vzb[om] = Xb[j * 3 + 2];
            vib[om] = j;
            ++om;
        }
    }
    __syncthreads();
    const int nv = stot;
    if (t == 0) nvarr[b] = nv;
    const float INF = __uint_as_float(0x7F800000u);
    for (int m = nv + t; m < NN; m += 256) {
        vxb[m] = INF; vyb[m] = INF; vzb[m] = INF; vib[m] = 0x7FFFFFFF;
    }
}

// ---------------- kNN via radix-select with early exit -----------------------
// Keys: (d2_bits << 32) | j. d2 >= 0 -> float bits monotonic as uint; keys
// unique (j); ascending (d2bits, j) == lax.top_k order incl. tie-break.
// Candidates = compacted valid nodes only (top-30 is always valid: ~4096 valid
// keys < 1e9 exist). Ladder drops the reference's "+0.0f" validity term for
// valid j (identity on finite d2 >= 0 -> bit-identical); self term compares
// the loaded original index. inf-pad and self keys have hb >= BIGBITS ->
// excluded from histogram and never collected (V << BIGBITS).
__global__ __launch_bounds__(256) void knn_kernel(const float* __restrict__ vx,
                                                  const float* __restrict__ vy,
                                                  const float* __restrict__ vz,
                                                  const int* __restrict__ vidx,
                                                  const int* __restrict__ nvarr,
                                                  const float* __restrict__ X,
                                                  int* __restrict__ edges) {
    const int row = blockIdx.x;          // 0..TOT-1 (block per row)
    const int b = row >> 13;
    const int i = row & (NN - 1);
    const float* vxb = vx + (size_t)b * NN;
    const float* vyb = vy + (size_t)b * NN;
    const float* vzb = vz + (size_t)b * NN;
    const int* vib = vidx + (size_t)b * NN;
    const float xi = X[(size_t)b * NN * 3 + i * 3 + 0];
    const float yi = X[(size_t)b * NN * 3 + i * 3 + 1];
    const float zi = X[(size_t)b * NN * 3 + i * 3 + 2];
    const int t = threadIdx.x;
    const uint32_t BIGBITS = __float_as_uint(1e9f);
    const int nv = nvarr[b];
    const int gmax = (nv + 1023) >> 10;  // block-uniform

    // d2 for compacted slot m = g*1024 + t*4 + q; unused slots = +inf
    float d[32];
#pragma unroll
    for (int s = 0; s < 32; ++s) d[s] = __uint_as_float(0x7F800000u);
#pragma unroll
    for (int g = 0; g < 8; ++g) {
        if (g < gmax) {
            const int j0 = g * 1024 + t * 4;
            const float4 x4 = *(const float4*)(vxb + j0);
            const float4 y4 = *(const float4*)(vyb + j0);
            const float4 z4 = *(const float4*)(vzb + j0);
            const int4 i4 = *(const int4*)(vib + j0);
#define D2(q, xx, yy, zz, jj)                                                  \
            {                                                                  \
                float dx = __fsub_rn(xi, (xx));                                \
                float dy = __fsub_rn(yi, (yy));                                \
                float dz = __fsub_rn(zi, (zz));                                \
                float d2 = __fadd_rn(__fadd_rn(__fmul_rn(dx, dx),              \
                                               __fmul_rn(dy, dy)),             \
                                     __fmul_rn(dz, dz));                       \
                d2 = __fadd_rn(d2, ((jj) == i) ? 1e9f : 0.0f);                 \
                d[g * 4 + (q)] = d2;                                           \
            }
            D2(0, x4.x, y4.x, z4.x, i4.x)
            D2(1, x4.y, y4.y, z4.y, i4.y)
            D2(2, x4.z, y4.z, z4.z, i4.z)
            D2(3, x4.w, y4.w, z4.w, i4.w)
#undef D2
        }
    }

    __shared__ uint32_t hist[16][257];   // 16 sub-hists, +1 pad breaks bank alias
    __shared__ uint32_t sel3[3];         // [0]=prefix, [1]=remaining rank, [2]=cB
    __shared__ unsigned long long cbuf[64];
    __shared__ uint32_t ccnt;

    const int sh = t >> 4;               // sub-histogram id (16 threads each)
    if (t == 0) { sel3[0] = 0u; sel3[1] = (uint32_t)KNB; sel3[2] = 0u; ccnt = 0u; }

    int exitShift = 0;                   // shift of the level we stopped at
    for (int L = 0; L < 4; ++L) {
        const int shift = 24 - 8 * L;
        const uint32_t pmask = (L == 0) ? 0u : (0xFFFFFFFFu << (32 - 8 * L));
        for (int q = 0; q < 16; ++q) hist[q][t] = 0u;
        __syncthreads();                 // also publishes sel3/ccnt init (L=0)
        const uint32_t pref = sel3[0];
#pragma unroll
        for (int s = 0; s < 32; ++s) {
            uint32_t hb = __float_as_uint(d[s]);
            if ((hb & pmask) == pref && hb < BIGBITS)
                atomicAdd(&hist[sh][(hb >> shift) & 255], 1u);
        }
        __syncthreads();
        uint32_t colsum = 0;
#pragma unroll
        for (int q = 0; q < 16; ++q) colsum += hist[q][t];
        hist[0][t] = colsum;
        __syncthreads();
        // wave 0: find bucket containing remaining rank r (1-indexed)
        if (t < 64) {
            uint32_t c0 = hist[0][4 * t + 0], c1 = hist[0][4 * t + 1];
            uint32_t c2 = hist[0][4 * t + 2], c3 = hist[0][4 * t + 3];
            uint32_t lsum = c0 + c1 + c2 + c3;
            uint32_t inc = lsum;
#pragma unroll
            for (int off = 1; off < 64; off <<= 1) {
                uint32_t o = __shfl_up(inc, off, 64);
                if (t >= off) inc += o;
            }
            uint32_t exc = inc - lsum;
            uint32_t r = sel3[1];
            if (exc < r && r <= inc) {   // exactly one lane brackets r
                uint32_t e = exc, bkt, cB;
                if (r <= e + c0)                { bkt = 4u * t + 0u; cB = c0; }
                else if (r <= e + c0 + c1)      { bkt = 4u * t + 1u; cB = c1; e += c0; }
                else if (r <= e + c0 + c1 + c2) { bkt = 4u * t + 2u; cB = c2; e += c0 + c1; }
                else                            { bkt = 4u * t + 3u; cB = c3; e += c0 + c1 + c2; }
                sel3[0] = pref | (bkt << shift);
                sel3[1] = r - e;         // rank within chosen bucket
                sel3[2] = cB;            // bucket population
            }
        }
        __syncthreads();
        // uniform early exit: collected set (below-prefix + bucket) fits cbuf
        if ((uint32_t)KNB - sel3[1] + sel3[2] <= 64u) { exitShift = shift; break; }
    }

    const uint32_t V = sel3[0] | ((exitShift > 0) ? ((1u << exitShift) - 1u) : 0u);
    // collect all keys with d2bits <= V (30 <= n <= 64 on early exit)
#pragma unroll
    for (int s = 0; s < 32; ++s) {
        uint32_t hb = __float_as_uint(d[s]);
        if (hb <= V) {
            const int m = (s >> 2) * 1024 + t * 4 + (s & 3);
            const int j = vib[m];
            uint32_t p = atomicAdd(&ccnt, 1u);
            if (p < 64u)
                cbuf[p] = (((unsigned long long)hb) << 32) | (unsigned)j;
        }
    }
    __syncthreads();
    const uint32_t n = ccnt < 64u ? ccnt : 64u;
    // wave 0: bitonic sort 64 via shfl (same network as proven sort_kernel)
    if (t < 64) {
        unsigned long long key = ((uint32_t)t < n) ? cbuf[t] : ~0ull;
#pragma unroll
        for (int k = 2; k <= 64; k <<= 1) {
            for (int j2 = k >> 1; j2 > 0; j2 >>= 1) {
                unsigned long long o = __shfl_xor(key, j2, 64);
                bool up = ((t & k) == 0);
                bool lower = ((t & j2) == 0);
                unsigned long long mn = key < o ? key : o;
                unsigned long long mx = key < o ? o : key;
                key = (up == lower) ? mn : mx;
            }
        }
        if (t < KNB) edges[(size_t)row * KNB + t] = (int)(key & 0xffffffffu);
    }
}

// ---------------- one smoothing step (all selected neighbors are valid) -------
__global__ void smooth_kernel(const float* __restrict__ zin,
                              float* __restrict__ zout,
                              const int* __restrict__ edges,
                              const int* __restrict__ C) {
    int t = blockIdx.x * blockDim.x + threadIdx.x;
    if (t >= TOT) return;
    float acc = 0.0f;
    if (C[t] > 0) {
        const int b = t >> 13;
        const int* e = edges + (size_t)t * KNB;
        const float* zb = zin + (size_t)b * NN;
#pragma unroll
        for (int k = 0; k < KNB; ++k) acc = __fadd_rn(acc, zb[e[k]]);
        acc = __fdiv_rn(acc, __fadd_rn(30.0f, 1e-5f));
    }
    zout[t] = acc;
}

// ---------------- z += priority; stable ascending argsort per batch ----------
__global__ __launch_bounds__(1024) void sort_kernel(const float* __restrict__ z,
                                                    const float* __restrict__ prio,
                                                    int* __restrict__ out) {
    __shared__ unsigned long long keys[NN];  // 64 KiB
    const int b = blockIdx.x;
    for (int i = threadIdx.x; i < NN; i += 1024) {
        float v = z[(size_t)b * NN + i] + prio[(size_t)b * NN + i];
        uint32_t u = __float_as_uint(v);
        u ^= (u >> 31) ? 0xFFFFFFFFu : 0x80000000u;  // monotonic float->uint
        keys[i] = ((unsigned long long)u << 32) | (unsigned)i;
    }
    __syncthreads();
    for (int k = 2; k <= NN; k <<= 1) {
        for (int j = k >> 1; j > 0; j >>= 1) {
            for (int i = threadIdx.x; i < NN; i += 1024) {
                int ixj = i ^ j;
                if (ixj > i) {
                    unsigned long long a = keys[i], c = keys[ixj];
                    bool up = ((i & k) == 0);
                    if ((a > c) == up) { keys[i] = c; keys[ixj] = a; }
                }
            }
            __syncthreads();
        }
    }
    for (int i = threadIdx.x; i < NN; i += 1024)
        out[(size_t)b * NN + i] = (int)(keys[i] & 0xffffffffu);
}

extern "C" void kernel_launch(void* const* d_in, const int* in_sizes, int n_in,
                              void* d_out, int out_size, void* d_ws, size_t ws_size,
                              hipStream_t stream) {
    const float* X = (const float*)d_in[0];    // [4,8192,3] f32
    const int* C = (const int*)d_in[1];        // [4,8192] int32
    const float* prio = (const float*)d_in[2]; // [4,8192] f32
    int* out = (int*)d_out;                    // [4,8192] i32

    float* z0 = (float*)d_ws;
    float* z1 = z0 + TOT;
    int* edges = (int*)(z1 + TOT);             // TOT*KNB ints
    float* vx = (float*)(edges + (size_t)TOT * KNB);
    float* vy = vx + (size_t)NB * NN;
    float* vz = vy + (size_t)NB * NN;
    int* vidx = (int*)(vz + (size_t)NB * NN);
    int* nvarr = vidx + (size_t)NB * NN;

    init_z_kernel<<<TOT / 256, 256, 0, stream>>>(z0);
    compact_kernel<<<NB, 256, 0, stream>>>(X, C, vx, vy, vz, vidx, nvarr);
    knn_kernel<<<TOT, 256, 0, stream>>>(vx, vy, vz, vidx, nvarr, X, edges);

    float* cur = z0;
    float* nxt = z1;
    for (int s = 0; s < 5; ++s) {
        smooth_kernel<<<TOT / 256, 256, 0, stream>>>(cur, nxt, edges, C);
        float* tmp = cur; cur = nxt; nxt = tmp;
    }
    sort_kernel<<<NB, 1024, 0, stream>>>(cur, prio, out);
}

// Round 13
// 494.100 us; speedup vs baseline: 1.6074x; 1.6074x over previous
//
#include <hip/hip_runtime.h>
#include <stdint.h>

#define NB 4
#define NN 8192
#define KNB 30
#define TOT (NB * NN)

// ---------------- threefry2x32 (JAX-exact, key = [0, 42]) ----------------
__device__ __forceinline__ uint32_t rotl32(uint32_t v, int r) {
    return (v << r) | (v >> (32 - r));
}

__device__ __forceinline__ void threefry(uint32_t x0, uint32_t x1,
                                         uint32_t& o0, uint32_t& o1) {
    const uint32_t ks0 = 0u, ks1 = 42u, ks2 = 0u ^ 42u ^ 0x1BD11BDAu;
    x0 += ks0; x1 += ks1;
#define RND(r) { x0 += x1; x1 = rotl32(x1, r); x1 ^= x0; }
    RND(13) RND(15) RND(26) RND(6)
    x0 += ks1; x1 += ks2 + 1u;
    RND(17) RND(29) RND(16) RND(24)
    x0 += ks2; x1 += ks0 + 2u;
    RND(13) RND(15) RND(26) RND(6)
    x0 += ks0; x1 += ks1 + 3u;
    RND(17) RND(29) RND(16) RND(24)
    x0 += ks1; x1 += ks2 + 4u;
    RND(13) RND(15) RND(26) RND(6)
    x0 += ks2; x1 += ks0 + 5u;
#undef RND
    o0 = x0; o1 = x1;
}

// jax_threefry_partitionable=True: bits[t] = o0^o1 of threefry(key, 0, t)
__global__ void init_z_kernel(float* __restrict__ z) {
    int t = blockIdx.x * blockDim.x + threadIdx.x;
    if (t >= TOT) return;
    uint32_t o0, o1;
    threefry(0u, (uint32_t)t, o0, o1);
    uint32_t bits = o0 ^ o1;
    z[t] = __uint_as_float((bits >> 9) | 0x3f800000u) - 1.0f;
}

// ---------------- SoA transpose: X[b][n][3] -> Xs[b][3][NN] ------------------
__global__ void transpose_kernel(const float* __restrict__ X,
                                 float* __restrict__ Xs) {
    int t = blockIdx.x * blockDim.x + threadIdx.x;
    if (t >= TOT) return;
    const int b = t >> 13, n = t & (NN - 1);
    const float* src = X + (size_t)b * NN * 3 + (size_t)n * 3;
    float* dst = Xs + (size_t)b * 3 * NN;
    dst[0 * NN + n] = src[0];
    dst[1 * NN + n] = src[1];
    dst[2 * NN + n] = src[2];
}

// ---------------- kNN via radix-select with early exit -----------------------
// Keys: (d2_bits << 32) | j. d2 >= 0 -> float bits monotonic as uint; keys
// unique (j); ascending (d2bits, j) == lax.top_k order incl. tie-break.
// Thread t owns j = g*1024 + t*4 + q (g<8, q<4), s = g*4+q. float4/int4 loads
// from SoA Xs; d2 ladder ops VERBATIM (bit-identical values).
// Histogram counts only keys with hb < bits(1e9) (invalid/self can't be top-30).
// Sub-hist id sh = t & 15: the 16 lanes of each group hit DISTINCT copies ->
// same-bucket atomics land in 16 distinct banks (257 % 32 == 1); same-address
// degree across wave64 drops 16 -> 4 (was sh = t>>4: 5.7e7 conflict cycles).
__global__ __launch_bounds__(256) void knn_kernel(const float* __restrict__ Xs,
                                                  const float* __restrict__ X,
                                                  const int* __restrict__ C,
                                                  int* __restrict__ edges) {
    const int row = blockIdx.x;          // 0..TOT-1 (block per row)
    const int b = row >> 13;
    const int i = row & (NN - 1);
    const float* Xsb = Xs + (size_t)b * 3 * NN;
    const int* Cb = C + (size_t)b * NN;
    const float xi = X[(size_t)b * NN * 3 + i * 3 + 0];
    const float yi = X[(size_t)b * NN * 3 + i * 3 + 1];
    const float zi = X[(size_t)b * NN * 3 + i * 3 + 2];
    const int t = threadIdx.x;
    const uint32_t BIGBITS = __float_as_uint(1e9f);

    // d2 for j = g*1024 + t*4 + q, exact reference op order (values identical
    // to the R4-proven ladder; only the load source/ownership changed)
    float d[32];
#pragma unroll
    for (int g = 0; g < 8; ++g) {
        const int j0 = g * 1024 + t * 4;
        const float4 x4 = *(const float4*)(Xsb + 0 * NN + j0);
        const float4 y4 = *(const float4*)(Xsb + 1 * NN + j0);
        const float4 z4 = *(const float4*)(Xsb + 2 * NN + j0);
        const int4 c4 = *(const int4*)(Cb + j0);
#define D2(q, xx, yy, zz, cc)                                                  \
        {                                                                      \
            float dx = __fsub_rn(xi, (xx));                                    \
            float dy = __fsub_rn(yi, (yy));                                    \
            float dz = __fsub_rn(zi, (zz));                                    \
            float d2 = __fadd_rn(__fadd_rn(__fmul_rn(dx, dx),                  \
                                           __fmul_rn(dy, dy)),                 \
                                 __fmul_rn(dz, dz));                           \
            d2 = __fadd_rn(d2, ((cc) > 0) ? 0.0f : 1e9f);                      \
            d2 = __fadd_rn(d2, ((j0 + (q)) == i) ? 1e9f : 0.0f);               \
            d[g * 4 + (q)] = d2;                                               \
        }
        D2(0, x4.x, y4.x, z4.x, c4.x)
        D2(1, x4.y, y4.y, z4.y, c4.y)
        D2(2, x4.z, y4.z, z4.z, c4.z)
        D2(3, x4.w, y4.w, z4.w, c4.w)
#undef D2
    }

#define MKKEY(s) ((((unsigned long long)__float_as_uint(d[(s)])) << 32) | \
                  (unsigned)((((s) >> 2) * 1024) + t * 4 + ((s) & 3)))

    __shared__ uint32_t hist[16][257];   // 16 copies; +1 pad: 257 % 32 == 1
    __shared__ uint32_t sel3[3];         // [0]=prefix, [1]=remaining rank, [2]=cB
    __shared__ unsigned long long cbuf[64];
    __shared__ uint32_t ccnt;

    const int sh = t & 15;               // DISTINCT copy per lane within group
    if (t == 0) { sel3[0] = 0u; sel3[1] = (uint32_t)KNB; sel3[2] = 0u; ccnt = 0u; }

    int exitShift = 0;                   // shift of the level we stopped at
    for (int L = 0; L < 4; ++L) {
        const int shift = 24 - 8 * L;
        const uint32_t pmask = (L == 0) ? 0u : (0xFFFFFFFFu << (32 - 8 * L));
        for (int q = 0; q < 16; ++q) hist[q][t] = 0u;
        __syncthreads();                 // also publishes sel3/ccnt init (L=0)
        const uint32_t pref = sel3[0];
#pragma unroll
        for (int s = 0; s < 32; ++s) {
            uint32_t hb = __float_as_uint(d[s]);
            if ((hb & pmask) == pref && hb < BIGBITS)
                atomicAdd(&hist[sh][(hb >> shift) & 255], 1u);
        }
        __syncthreads();
        uint32_t colsum = 0;
#pragma unroll
        for (int q = 0; q < 16; ++q) colsum += hist[q][t];
        hist[0][t] = colsum;
        __syncthreads();
        // wave 0: find bucket containing remaining rank r (1-indexed)
        if (t < 64) {
            uint32_t c0 = hist[0][4 * t + 0], c1 = hist[0][4 * t + 1];
            uint32_t c2 = hist[0][4 * t + 2], c3 = hist[0][4 * t + 3];
            uint32_t lsum = c0 + c1 + c2 + c3;
            uint32_t inc = lsum;
#pragma unroll
            for (int off = 1; off < 64; off <<= 1) {
                uint32_t o = __shfl_up(inc, off, 64);
                if (t >= off) inc += o;
            }
            uint32_t exc = inc - lsum;
            uint32_t r = sel3[1];
            if (exc < r && r <= inc) {   // exactly one lane brackets r
                uint32_t e = exc, bkt, cB;
                if (r <= e + c0)                { bkt = 4u * t + 0u; cB = c0; }
                else if (r <= e + c0 + c1)      { bkt = 4u * t + 1u; cB = c1; e += c0; }
                else if (r <= e + c0 + c1 + c2) { bkt = 4u * t + 2u; cB = c2; e += c0 + c1; }
                else                            { bkt = 4u * t + 3u; cB = c3; e += c0 + c1 + c2; }
                sel3[0] = pref | (bkt << shift);
                sel3[1] = r - e;         // rank within chosen bucket
                sel3[2] = cB;            // bucket population
            }
        }
        __syncthreads();
        // uniform early exit: collected set (below-prefix + bucket) fits cbuf
        if ((uint32_t)KNB - sel3[1] + sel3[2] <= 64u) { exitShift = shift; break; }
    }

    const uint32_t V = sel3[0] | ((exitShift > 0) ? ((1u << exitShift) - 1u) : 0u);
    // collect all keys with d2bits <= V (30 <= n <= 64 on early exit)
#pragma unroll
    for (int s = 0; s < 32; ++s) {
        uint32_t hb = __float_as_uint(d[s]);
        if (hb <= V) {
            uint32_t p = atomicAdd(&ccnt, 1u);
            if (p < 64u) cbuf[p] = MKKEY(s);
        }
    }
#undef MKKEY
    __syncthreads();
    const uint32_t n = ccnt < 64u ? ccnt : 64u;
    // wave 0: bitonic sort 64 via shfl (same network as proven sort_kernel)
    if (t < 64) {
        unsigned long long key = ((uint32_t)t < n) ? cbuf[t] : ~0ull;
#pragma unroll
        for (int k = 2; k <= 64; k <<= 1) {
            for (int j2 = k >> 1; j2 > 0; j2 >>= 1) {
                unsigned long long o = __shfl_xor(key, j2, 64);
                bool up = ((t & k) == 0);
                bool lower = ((t & j2) == 0);
                unsigned long long mn = key < o ? key : o;
                unsigned long long mx = key < o ? o : key;
                key = (up == lower) ? mn : mx;
            }
        }
        if (t < KNB) edges[(size_t)row * KNB + t] = (int)(key & 0xffffffffu);
    }
}

// ---------------- one smoothing step (all selected neighbors are valid) -------
__global__ void smooth_kernel(const float* __restrict__ zin,
                              float* __restrict__ zout,
                              const int* __restrict__ edges,
                              const int* __restrict__ C) {
    int t = blockIdx.x * blockDim.x + threadIdx.x;
    if (t >= TOT) return;
    float acc = 0.0f;
    if (C[t] > 0) {
        const int b = t >> 13;
        const int* e = edges + (size_t)t * KNB;
        const float* zb = zin + (size_t)b * NN;
#pragma unroll
        for (int k = 0; k < KNB; ++k) acc = __fadd_rn(acc, zb[e[k]]);
        acc = __fdiv_rn(acc, __fadd_rn(30.0f, 1e-5f));
    }
    zout[t] = acc;
}

// ---------------- z += priority; stable ascending argsort per batch ----------
__global__ __launch_bounds__(1024) void sort_kernel(const float* __restrict__ z,
                                                    const float* __restrict__ prio,
                                                    int* __restrict__ out) {
    __shared__ unsigned long long keys[NN];  // 64 KiB
    const int b = blockIdx.x;
    for (int i = threadIdx.x; i < NN; i += 1024) {
        float v = z[(size_t)b * NN + i] + prio[(size_t)b * NN + i];
        uint32_t u = __float_as_uint(v);
        u ^= (u >> 31) ? 0xFFFFFFFFu : 0x80000000u;  // monotonic float->uint
        keys[i] = ((unsigned long long)u << 32) | (unsigned)i;
    }
    __syncthreads();
    for (int k = 2; k <= NN; k <<= 1) {
        for (int j = k >> 1; j > 0; j >>= 1) {
            for (int i = threadIdx.x; i < NN; i += 1024) {
                int ixj = i ^ j;
                if (ixj > i) {
                    unsigned long long a = keys[i], c = keys[ixj];
                    bool up = ((i & k) == 0);
                    if ((a > c) == up) { keys[i] = c; keys[ixj] = a; }
                }
            }
            __syncthreads();
        }
    }
    for (int i = threadIdx.x; i < NN; i += 1024)
        out[(size_t)b * NN + i] = (int)(keys[i] & 0xffffffffu);
}

extern "C" void kernel_launch(void* const* d_in, const int* in_sizes, int n_in,
                              void* d_out, int out_size, void* d_ws, size_t ws_size,
                              hipStream_t stream) {
    const float* X = (const float*)d_in[0];    // [4,8192,3] f32
    const int* C = (const int*)d_in[1];        // [4,8192] int32
    const float* prio = (const float*)d_in[2]; // [4,8192] f32
    int* out = (int*)d_out;                    // [4,8192] i32

    float* z0 = (float*)d_ws;
    float* z1 = z0 + TOT;
    int* edges = (int*)(z1 + TOT);             // TOT*30 ints
    float* Xs = (float*)(edges + (size_t)TOT * KNB);  // [NB][3][NN]

    init_z_kernel<<<TOT / 256, 256, 0, stream>>>(z0);
    transpose_kernel<<<TOT / 256, 256, 0, stream>>>(X, Xs);
    knn_kernel<<<TOT, 256, 0, stream>>>(Xs, X, C, edges);

    float* cur = z0;
    float* nxt = z1;
    for (int s = 0; s < 5; ++s) {
        smooth_kernel<<<TOT / 256, 256, 0, stream>>>(cur, nxt, edges, C);
        float* tmp = cur; cur = nxt; nxt = tmp;
    }
    sort_kernel<<<NB, 1024, 0, stream>>>(cur, prio, out);
}

// Round 14
// 405.385 us; speedup vs baseline: 1.9592x; 1.2188x over previous
//
#include <hip/hip_runtime.h>
#include <stdint.h>

#define NB 4
#define NN 8192
#define KNB 30
#define TOT (NB * NN)

// ---------------- threefry2x32 (JAX-exact, key = [0, 42]) ----------------
__device__ __forceinline__ uint32_t rotl32(uint32_t v, int r) {
    return (v << r) | (v >> (32 - r));
}

__device__ __forceinline__ void threefry(uint32_t x0, uint32_t x1,
                                         uint32_t& o0, uint32_t& o1) {
    const uint32_t ks0 = 0u, ks1 = 42u, ks2 = 0u ^ 42u ^ 0x1BD11BDAu;
    x0 += ks0; x1 += ks1;
#define RND(r) { x0 += x1; x1 = rotl32(x1, r); x1 ^= x0; }
    RND(13) RND(15) RND(26) RND(6)
    x0 += ks1; x1 += ks2 + 1u;
    RND(17) RND(29) RND(16) RND(24)
    x0 += ks2; x1 += ks0 + 2u;
    RND(13) RND(15) RND(26) RND(6)
    x0 += ks0; x1 += ks1 + 3u;
    RND(17) RND(29) RND(16) RND(24)
    x0 += ks1; x1 += ks2 + 4u;
    RND(13) RND(15) RND(26) RND(6)
    x0 += ks2; x1 += ks0 + 5u;
#undef RND
    o0 = x0; o1 = x1;
}

// ---- fused: z init (partitionable threefry) + SoA transpose w/ inf-baking ----
// Invalid candidates (C<=0) get +inf coords: their d2 becomes +inf, which is
// >= bits(1e9) -> excluded from histogram/collect exactly like the reference's
// d2+1e9 (cannot be top-30: ~4096 valid candidates exist). Valid candidates'
// ladder then drops only the "+0.0f" identity term -> bit-identical d2.
__global__ void prep_kernel(const float* __restrict__ X,
                            const int* __restrict__ C,
                            float* __restrict__ z,
                            float* __restrict__ Xs) {
    int t = blockIdx.x * blockDim.x + threadIdx.x;
    if (t >= TOT) return;
    uint32_t o0, o1;
    threefry(0u, (uint32_t)t, o0, o1);
    uint32_t bits = o0 ^ o1;
    z[t] = __uint_as_float((bits >> 9) | 0x3f800000u) - 1.0f;

    const int b = t >> 13, n = t & (NN - 1);
    const bool valid = C[t] > 0;
    const float INF = __uint_as_float(0x7F800000u);
    const float* src = X + (size_t)t * 3;
    float* dst = Xs + (size_t)b * 3 * NN;
    dst[0 * NN + n] = valid ? src[0] : INF;
    dst[1 * NN + n] = valid ? src[1] : INF;
    dst[2 * NN + n] = valid ? src[2] : INF;
}

// ---------------- kNN via radix-select with early exit -----------------------
// Keys: (d2_bits << 32) | j. d2 >= 0 -> float bits monotonic as uint; keys
// unique (j); ascending (d2bits, j) == lax.top_k order incl. tie-break.
// Thread t owns j = g*1024 + t*4 + q (g<8, q<4), s = g*4+q. float4 loads from
// inf-baked SoA Xs (no C loads). hb < bits(1e9) gates invalid/self out of the
// histogram. sh = t & 15 -> same-bucket atomics hit 16 distinct banks (R13).
// Per level: atomics, sync, {colsum->colrow + zero own column}, sync,
// ALL-WAVE scan in registers (ballot+shfl broadcast) -> 2 syncs/level.
__global__ __launch_bounds__(256) void knn_kernel(const float* __restrict__ Xs,
                                                  const float* __restrict__ X,
                                                  int* __restrict__ edgesT) {
    const int row = blockIdx.x;          // 0..TOT-1 (block per row)
    const int b = row >> 13;
    const int i = row & (NN - 1);
    const float* Xsb = Xs + (size_t)b * 3 * NN;
    const float xi = X[(size_t)b * NN * 3 + i * 3 + 0];
    const float yi = X[(size_t)b * NN * 3 + i * 3 + 1];
    const float zi = X[(size_t)b * NN * 3 + i * 3 + 2];
    const int t = threadIdx.x;
    const uint32_t BIGBITS = __float_as_uint(1e9f);

    float d[32];
#pragma unroll
    for (int g = 0; g < 8; ++g) {
        const int j0 = g * 1024 + t * 4;
        const float4 x4 = *(const float4*)(Xsb + 0 * NN + j0);
        const float4 y4 = *(const float4*)(Xsb + 1 * NN + j0);
        const float4 z4 = *(const float4*)(Xsb + 2 * NN + j0);
#define D2(q, xx, yy, zz)                                                      \
        {                                                                      \
            float dx = __fsub_rn(xi, (xx));                                    \
            float dy = __fsub_rn(yi, (yy));                                    \
            float dz = __fsub_rn(zi, (zz));                                    \
            float d2 = __fadd_rn(__fadd_rn(__fmul_rn(dx, dx),                  \
                                           __fmul_rn(dy, dy)),                 \
                                 __fmul_rn(dz, dz));                           \
            d2 = __fadd_rn(d2, ((j0 + (q)) == i) ? 1e9f : 0.0f);               \
            d[g * 4 + (q)] = d2;                                               \
        }
        D2(0, x4.x, y4.x, z4.x)
        D2(1, x4.y, y4.y, z4.y)
        D2(2, x4.z, y4.z, z4.z)
        D2(3, x4.w, y4.w, z4.w)
#undef D2
    }

#define MKKEY(s) ((((unsigned long long)__float_as_uint(d[(s)])) << 32) | \
                  (unsigned)((((s) >> 2) * 1024) + t * 4 + ((s) & 3)))

    __shared__ uint32_t hist[16][257];   // 16 copies; +1 pad: 257 % 32 == 1
    __shared__ uint32_t colrow[256];
    __shared__ unsigned long long cbuf[64];
    __shared__ uint32_t ccnt;

    const int sh = t & 15;               // distinct copy per lane within group
    const int l = t & 63;                // lane
    if (t == 0) ccnt = 0u;
#pragma unroll
    for (int q = 0; q < 16; ++q) hist[q][t] = 0u;
    __syncthreads();

    uint32_t pref = 0u, r = (uint32_t)KNB, cB = 0u;
    int exitShift = 0;
    for (int L = 0; L < 4; ++L) {
        const int shift = 24 - 8 * L;
        const uint32_t pmask = (L == 0) ? 0u : (0xFFFFFFFFu << (32 - 8 * L));
#pragma unroll
        for (int s = 0; s < 32; ++s) {
            uint32_t hb = __float_as_uint(d[s]);
            if ((hb & pmask) == pref && hb < BIGBITS)
                atomicAdd(&hist[sh][(hb >> shift) & 255], 1u);
        }
        __syncthreads();
        // colsum into colrow[t] and zero own column (exclusive to thread t)
        uint32_t colsum = 0;
#pragma unroll
        for (int q = 0; q < 16; ++q) { colsum += hist[q][t]; hist[q][t] = 0u; }
        colrow[t] = colsum;
        __syncthreads();
        // all-wave redundant scan (each wave computes identical result)
        uint32_t c0 = colrow[4 * l + 0], c1 = colrow[4 * l + 1];
        uint32_t c2 = colrow[4 * l + 2], c3 = colrow[4 * l + 3];
        uint32_t lsum = c0 + c1 + c2 + c3;
        uint32_t inc = lsum;
#pragma unroll
        for (int off = 1; off < 64; off <<= 1) {
            uint32_t o = __shfl_up(inc, off, 64);
            if (l >= off) inc += o;
        }
        uint32_t exc = inc - lsum;
        bool hit = (exc < r && r <= inc);
        unsigned long long mb = __ballot(hit);
        if (mb != 0ull) {
            uint32_t bkt = 0u, rnew = 0u, cBn = 0u;
            if (hit) {
                uint32_t e = exc;
                if (r <= e + c0)                { bkt = 4u * l + 0u; cBn = c0; }
                else if (r <= e + c0 + c1)      { bkt = 4u * l + 1u; cBn = c1; e += c0; }
                else if (r <= e + c0 + c1 + c2) { bkt = 4u * l + 2u; cBn = c2; e += c0 + c1; }
                else                            { bkt = 4u * l + 3u; cBn = c3; e += c0 + c1 + c2; }
                rnew = r - e;
            }
            const int src = (int)(__ffsll((long long)mb) - 1);
            bkt = __shfl(bkt, src, 64);
            rnew = __shfl(rnew, src, 64);
            cBn = __shfl(cBn, src, 64);
            pref = pref | (bkt << shift);
            r = rnew;
            cB = cBn;
        }
        if ((uint32_t)KNB - r + cB <= 64u) { exitShift = shift; break; }
    }

    const uint32_t V = pref | ((exitShift > 0) ? ((1u << exitShift) - 1u) : 0u);
    // collect all keys with d2bits <= V (30 <= n <= 64 on early exit)
#pragma unroll
    for (int s = 0; s < 32; ++s) {
        uint32_t hb = __float_as_uint(d[s]);
        if (hb <= V) {
            uint32_t p = atomicAdd(&ccnt, 1u);
            if (p < 64u) cbuf[p] = MKKEY(s);
        }
    }
#undef MKKEY
    __syncthreads();
    const uint32_t n = ccnt < 64u ? ccnt : 64u;
    // wave 0: bitonic sort 64 via shfl (same network as proven sort_kernel)
    if (t < 64) {
        unsigned long long key = ((uint32_t)t < n) ? cbuf[t] : ~0ull;
#pragma unroll
        for (int k = 2; k <= 64; k <<= 1) {
            for (int j2 = k >> 1; j2 > 0; j2 >>= 1) {
                unsigned long long o = __shfl_xor(key, j2, 64);
                bool up = ((t & k) == 0);
                bool lower = ((t & j2) == 0);
                unsigned long long mn = key < o ? key : o;
                unsigned long long mx = key < o ? o : key;
                key = (up == lower) ? mn : mx;
            }
        }
        if (t < KNB) edgesT[(size_t)t * TOT + row] = (int)(key & 0xffffffffu);
    }
}

// ------- one smoothing step (edgesT[k][row]: coalesced neighbor loads) -------
__global__ void smooth_kernel(const float* __restrict__ zin,
                              float* __restrict__ zout,
                              const int* __restrict__ edgesT,
                              const int* __restrict__ C) {
    int t = blockIdx.x * blockDim.x + threadIdx.x;
    if (t >= TOT) return;
    float acc = 0.0f;
    if (C[t] > 0) {
        const int b = t >> 13;
        const float* zb = zin + (size_t)b * NN;
#pragma unroll
        for (int k = 0; k < KNB; ++k)
            acc = __fadd_rn(acc, zb[edgesT[(size_t)k * TOT + t]]);
        acc = __fdiv_rn(acc, __fadd_rn(30.0f, 1e-5f));
    }
    zout[t] = acc;
}

// ---------------- z += priority; stable ascending argsort per batch ----------
__global__ __launch_bounds__(1024) void sort_kernel(const float* __restrict__ z,
                                                    const float* __restrict__ prio,
                                                    int* __restrict__ out) {
    __shared__ unsigned long long keys[NN];  // 64 KiB
    const int b = blockIdx.x;
    for (int i = threadIdx.x; i < NN; i += 1024) {
        float v = z[(size_t)b * NN + i] + prio[(size_t)b * NN + i];
        uint32_t u = __float_as_uint(v);
        u ^= (u >> 31) ? 0xFFFFFFFFu : 0x80000000u;  // monotonic float->uint
        keys[i] = ((unsigned long long)u << 32) | (unsigned)i;
    }
    __syncthreads();
    for (int k = 2; k <= NN; k <<= 1) {
        for (int j = k >> 1; j > 0; j >>= 1) {
            for (int i = threadIdx.x; i < NN; i += 1024) {
                int ixj = i ^ j;
                if (ixj > i) {
                    unsigned long long a = keys[i], c = keys[ixj];
                    bool up = ((i & k) == 0);
                    if ((a > c) == up) { keys[i] = c; keys[ixj] = a; }
                }
            }
            __syncthreads();
        }
    }
    for (int i = threadIdx.x; i < NN; i += 1024)
        out[(size_t)b * NN + i] = (int)(keys[i] & 0xffffffffu);
}

extern "C" void kernel_launch(void* const* d_in, const int* in_sizes, int n_in,
                              void* d_out, int out_size, void* d_ws, size_t ws_size,
                              hipStream_t stream) {
    const float* X = (const float*)d_in[0];    // [4,8192,3] f32
    const int* C = (const int*)d_in[1];        // [4,8192] int32
    const float* prio = (const float*)d_in[2]; // [4,8192] f32
    int* out = (int*)d_out;                    // [4,8192] i32

    float* z0 = (float*)d_ws;
    float* z1 = z0 + TOT;
    int* edgesT = (int*)(z1 + TOT);            // [KNB][TOT]
    float* Xs = (float*)(edgesT + (size_t)TOT * KNB);  // [NB][3][NN]

    prep_kernel<<<TOT / 256, 256, 0, stream>>>(X, C, z0, Xs);
    knn_kernel<<<TOT, 256, 0, stream>>>(Xs, X, edgesT);

    float* cur = z0;
    float* nxt = z1;
    for (int s = 0; s < 5; ++s) {
        smooth_kernel<<<TOT / 256, 256, 0, stream>>>(cur, nxt, edgesT, C);
        float* tmp = cur; cur = nxt; nxt = tmp;
    }
    sort_kernel<<<NB, 1024, 0, stream>>>(cur, prio, out);
}

// Round 15
// 378.329 us; speedup vs baseline: 2.0993x; 1.0715x over previous
//
#include <hip/hip_runtime.h>
#include <stdint.h>

#define NB 4
#define NN 8192
#define KNB 30
#define TOT (NB * NN)

// ---------------- threefry2x32 (JAX-exact, key = [0, 42]) ----------------
__device__ __forceinline__ uint32_t rotl32(uint32_t v, int r) {
    return (v << r) | (v >> (32 - r));
}

__device__ __forceinline__ void threefry(uint32_t x0, uint32_t x1,
                                         uint32_t& o0, uint32_t& o1) {
    const uint32_t ks0 = 0u, ks1 = 42u, ks2 = 0u ^ 42u ^ 0x1BD11BDAu;
    x0 += ks0; x1 += ks1;
#define RND(r) { x0 += x1; x1 = rotl32(x1, r); x1 ^= x0; }
    RND(13) RND(15) RND(26) RND(6)
    x0 += ks1; x1 += ks2 + 1u;
    RND(17) RND(29) RND(16) RND(24)
    x0 += ks2; x1 += ks0 + 2u;
    RND(13) RND(15) RND(26) RND(6)
    x0 += ks0; x1 += ks1 + 3u;
    RND(17) RND(29) RND(16) RND(24)
    x0 += ks1; x1 += ks2 + 4u;
    RND(13) RND(15) RND(26) RND(6)
    x0 += ks2; x1 += ks0 + 5u;
#undef RND
    o0 = x0; o1 = x1;
}

// ---- fused: z init (partitionable threefry) + SoA transpose w/ inf-baking ----
__global__ void prep_kernel(const float* __restrict__ X,
                            const int* __restrict__ C,
                            float* __restrict__ z,
                            float* __restrict__ Xs) {
    int t = blockIdx.x * blockDim.x + threadIdx.x;
    if (t >= TOT) return;
    uint32_t o0, o1;
    threefry(0u, (uint32_t)t, o0, o1);
    uint32_t bits = o0 ^ o1;
    z[t] = __uint_as_float((bits >> 9) | 0x3f800000u) - 1.0f;

    const int b = t >> 13, n = t & (NN - 1);
    const bool valid = C[t] > 0;
    const float INF = __uint_as_float(0x7F800000u);
    const float* src = X + (size_t)t * 3;
    float* dst = Xs + (size_t)b * 3 * NN;
    dst[0 * NN + n] = valid ? src[0] : INF;
    dst[1 * NN + n] = valid ? src[1] : INF;
    dst[2 * NN + n] = valid ? src[2] : INF;
}

// ---------------- kNN: windowed single-level radix-select --------------------
// Keys: (d2_bits << 32) | j, unique, ascending == lax.top_k order w/ tie-break.
// Fast path: block-min M of d2 bits; bucket = min(255, (hb>>20) - (Mb>>20))
// (monotone, 1/8-octave granularity, 32-octave span). Rank-30 bucket found by
// one scan; if below+cB <= 64 collect hb <= V, V = ((base+bkt+1)<<20)-1
// (< inf bits -> pad/self/invalid auto-excluded). Else: VERBATIM R14 4-level
// loop (proven exact). Both paths exact; block-uniform branch.
__global__ __launch_bounds__(256) void knn_kernel(const float* __restrict__ Xs,
                                                  const float* __restrict__ X,
                                                  int* __restrict__ edgesT) {
    const int row = blockIdx.x;          // 0..TOT-1 (block per row)
    const int b = row >> 13;
    const int i = row & (NN - 1);
    const float* Xsb = Xs + (size_t)b * 3 * NN;
    const float xi = X[(size_t)b * NN * 3 + i * 3 + 0];
    const float yi = X[(size_t)b * NN * 3 + i * 3 + 1];
    const float zi = X[(size_t)b * NN * 3 + i * 3 + 2];
    const int t = threadIdx.x;
    const uint32_t BIGBITS = __float_as_uint(1e9f);

    float d[32];
#pragma unroll
    for (int g = 0; g < 8; ++g) {
        const int j0 = g * 1024 + t * 4;
        const float4 x4 = *(const float4*)(Xsb + 0 * NN + j0);
        const float4 y4 = *(const float4*)(Xsb + 1 * NN + j0);
        const float4 z4 = *(const float4*)(Xsb + 2 * NN + j0);
#define D2(q, xx, yy, zz)                                                      \
        {                                                                      \
            float dx = __fsub_rn(xi, (xx));                                    \
            float dy = __fsub_rn(yi, (yy));                                    \
            float dz = __fsub_rn(zi, (zz));                                    \
            float d2 = __fadd_rn(__fadd_rn(__fmul_rn(dx, dx),                  \
                                           __fmul_rn(dy, dy)),                 \
                                 __fmul_rn(dz, dz));                           \
            d2 = __fadd_rn(d2, ((j0 + (q)) == i) ? 1e9f : 0.0f);               \
            d[g * 4 + (q)] = d2;                                               \
        }
        D2(0, x4.x, y4.x, z4.x)
        D2(1, x4.y, y4.y, z4.y)
        D2(2, x4.z, y4.z, z4.z)
        D2(3, x4.w, y4.w, z4.w)
#undef D2
    }

#define MKKEY(s) ((((unsigned long long)__float_as_uint(d[(s)])) << 32) | \
                  (unsigned)((((s) >> 2) * 1024) + t * 4 + ((s) & 3)))

    __shared__ uint32_t hist[16][257];   // 16 copies; +1 pad: 257 % 32 == 1
    __shared__ uint32_t colrow[256];
    __shared__ float wmin[4];
    __shared__ unsigned long long cbuf[64];
    __shared__ uint32_t ccnt;

    const int sh = t & 15;               // distinct copy per lane within group
    const int l = t & 63;                // lane
    const int w = t >> 6;                // wave
    if (t == 0) ccnt = 0u;
#pragma unroll
    for (int q = 0; q < 16; ++q) hist[q][t] = 0u;

    // block-min of d2 (floats all >= 0, no NaN -> float min == bits min)
    float mn = d[0];
#pragma unroll
    for (int s = 1; s < 32; ++s) mn = fminf(mn, d[s]);
#pragma unroll
    for (int off = 32; off >= 1; off >>= 1)
        mn = fminf(mn, __shfl_xor(mn, off, 64));
    if (l == 0) wmin[w] = mn;
    __syncthreads();                     // publishes wmin, hist zero, ccnt
    const uint32_t Mb = __float_as_uint(
        fminf(fminf(wmin[0], wmin[1]), fminf(wmin[2], wmin[3])));
    const uint32_t base = Mb >> 20;

    // windowed histogram level
#pragma unroll
    for (int s = 0; s < 32; ++s) {
        uint32_t hb = __float_as_uint(d[s]);
        if (hb < BIGBITS) {
            uint32_t bs = (hb >> 20) - base;
            bs = bs < 255u ? bs : 255u;
            atomicAdd(&hist[sh][bs], 1u);
        }
    }
    __syncthreads();
    uint32_t colsum = 0;
#pragma unroll
    for (int q = 0; q < 16; ++q) { colsum += hist[q][t]; hist[q][t] = 0u; }
    colrow[t] = colsum;
    __syncthreads();
    // all-wave redundant scan (each wave computes identical result)
    uint32_t bktW = 0u, rW = 0u, cBW = 0u;
    {
        uint32_t c0 = colrow[4 * l + 0], c1 = colrow[4 * l + 1];
        uint32_t c2 = colrow[4 * l + 2], c3 = colrow[4 * l + 3];
        uint32_t lsum = c0 + c1 + c2 + c3;
        uint32_t inc = lsum;
#pragma unroll
        for (int off = 1; off < 64; off <<= 1) {
            uint32_t o = __shfl_up(inc, off, 64);
            if (l >= off) inc += o;
        }
        uint32_t exc = inc - lsum;
        const uint32_t r = (uint32_t)KNB;
        bool hit = (exc < r && r <= inc);
        unsigned long long mb = __ballot(hit);
        uint32_t bkt = 0u, rnew = 0u, cBn = 0u;
        if (hit) {
            uint32_t e = exc;
            if (r <= e + c0)                { bkt = 4u * l + 0u; cBn = c0; }
            else if (r <= e + c0 + c1)      { bkt = 4u * l + 1u; cBn = c1; e += c0; }
            else if (r <= e + c0 + c1 + c2) { bkt = 4u * l + 2u; cBn = c2; e += c0 + c1; }
            else                            { bkt = 4u * l + 3u; cBn = c3; e += c0 + c1 + c2; }
            rnew = r - e;
        }
        const int src = (int)(__ffsll((long long)mb) - 1);
        bktW = __shfl(bkt, src, 64);
        rW = __shfl(rnew, src, 64);
        cBW = __shfl(cBn, src, 64);
    }

    uint32_t V;
    if (bktW < 255u && (uint32_t)KNB - rW + cBW <= 64u) {
        // fast path: exact conservative threshold from the window bucket
        V = ((base + bktW + 1u) << 20) - 1u;   // < 0x7F800000 always
    } else {
        // slow fallback: VERBATIM R14 4-level radix-select (hist already zero)
        __syncthreads();
        uint32_t pref = 0u, r = (uint32_t)KNB, cB = 0u;
        int exitShift = 0;
        for (int L = 0; L < 4; ++L) {
            const int shift = 24 - 8 * L;
            const uint32_t pmask = (L == 0) ? 0u : (0xFFFFFFFFu << (32 - 8 * L));
#pragma unroll
            for (int s = 0; s < 32; ++s) {
                uint32_t hb = __float_as_uint(d[s]);
                if ((hb & pmask) == pref && hb < BIGBITS)
                    atomicAdd(&hist[sh][(hb >> shift) & 255], 1u);
            }
            __syncthreads();
            uint32_t cs = 0;
#pragma unroll
            for (int q = 0; q < 16; ++q) { cs += hist[q][t]; hist[q][t] = 0u; }
            colrow[t] = cs;
            __syncthreads();
            uint32_t c0 = colrow[4 * l + 0], c1 = colrow[4 * l + 1];
            uint32_t c2 = colrow[4 * l + 2], c3 = colrow[4 * l + 3];
            uint32_t lsum = c0 + c1 + c2 + c3;
            uint32_t inc = lsum;
#pragma unroll
            for (int off = 1; off < 64; off <<= 1) {
                uint32_t o = __shfl_up(inc, off, 64);
                if (l >= off) inc += o;
            }
            uint32_t exc = inc - lsum;
            bool hit = (exc < r && r <= inc);
            unsigned long long mb = __ballot(hit);
            if (mb != 0ull) {
                uint32_t bkt = 0u, rnew = 0u, cBn = 0u;
                if (hit) {
                    uint32_t e = exc;
                    if (r <= e + c0)                { bkt = 4u * l + 0u; cBn = c0; }
                    else if (r <= e + c0 + c1)      { bkt = 4u * l + 1u; cBn = c1; e += c0; }
                    else if (r <= e + c0 + c1 + c2) { bkt = 4u * l + 2u; cBn = c2; e += c0 + c1; }
                    else                            { bkt = 4u * l + 3u; cBn = c3; e += c0 + c1 + c2; }
                    rnew = r - e;
                }
                const int src = (int)(__ffsll((long long)mb) - 1);
                bkt = __shfl(bkt, src, 64);
                rnew = __shfl(rnew, src, 64);
                cBn = __shfl(cBn, src, 64);
                pref = pref | (bkt << shift);
                r = rnew;
                cB = cBn;
            }
            if ((uint32_t)KNB - r + cB <= 64u) { exitShift = shift; break; }
        }
        V = pref | ((exitShift > 0) ? ((1u << exitShift) - 1u) : 0u);
    }

    // collect all keys with d2bits <= V (30 <= n <= 64)
#pragma unroll
    for (int s = 0; s < 32; ++s) {
        uint32_t hb = __float_as_uint(d[s]);
        if (hb <= V) {
            uint32_t p = atomicAdd(&ccnt, 1u);
            if (p < 64u) cbuf[p] = MKKEY(s);
        }
    }
#undef MKKEY
    __syncthreads();
    const uint32_t n = ccnt < 64u ? ccnt : 64u;
    // wave 0: bitonic sort 64 via shfl (same network as proven sort_kernel)
    if (t < 64) {
        unsigned long long key = ((uint32_t)t < n) ? cbuf[t] : ~0ull;
#pragma unroll
        for (int k = 2; k <= 64; k <<= 1) {
            for (int j2 = k >> 1; j2 > 0; j2 >>= 1) {
                unsigned long long o = __shfl_xor(key, j2, 64);
                bool up = ((t & k) == 0);
                bool lower = ((t & j2) == 0);
                unsigned long long mn2 = key < o ? key : o;
                unsigned long long mx = key < o ? o : key;
                key = (up == lower) ? mn2 : mx;
            }
        }
        if (t < KNB) edgesT[(size_t)t * TOT + row] = (int)(key & 0xffffffffu);
    }
}

// ------- one smoothing step (edgesT[k][row]: coalesced neighbor loads) -------
__global__ void smooth_kernel(const float* __restrict__ zin,
                              float* __restrict__ zout,
                              const int* __restrict__ edgesT,
                              const int* __restrict__ C) {
    int t = blockIdx.x * blockDim.x + threadIdx.x;
    if (t >= TOT) return;
    float acc = 0.0f;
    if (C[t] > 0) {
        const int b = t >> 13;
        const float* zb = zin + (size_t)b * NN;
#pragma unroll
        for (int k = 0; k < KNB; ++k)
            acc = __fadd_rn(acc, zb[edgesT[(size_t)k * TOT + t]]);
        acc = __fdiv_rn(acc, __fadd_rn(30.0f, 1e-5f));
    }
    zout[t] = acc;
}

// ---------------- z += priority; stable ascending argsort per batch ----------
__global__ __launch_bounds__(1024) void sort_kernel(const float* __restrict__ z,
                                                    const float* __restrict__ prio,
                                                    int* __restrict__ out) {
    __shared__ unsigned long long keys[NN];  // 64 KiB
    const int b = blockIdx.x;
    for (int i = threadIdx.x; i < NN; i += 1024) {
        float v = z[(size_t)b * NN + i] + prio[(size_t)b * NN + i];
        uint32_t u = __float_as_uint(v);
        u ^= (u >> 31) ? 0xFFFFFFFFu : 0x80000000u;  // monotonic float->uint
        keys[i] = ((unsigned long long)u << 32) | (unsigned)i;
    }
    __syncthreads();
    for (int k = 2; k <= NN; k <<= 1) {
        for (int j = k >> 1; j > 0; j >>= 1) {
            for (int i = threadIdx.x; i < NN; i += 1024) {
                int ixj = i ^ j;
                if (ixj > i) {
                    unsigned long long a = keys[i], c = keys[ixj];
                    bool up = ((i & k) == 0);
                    if ((a > c) == up) { keys[i] = c; keys[ixj] = a; }
                }
            }
            __syncthreads();
        }
    }
    for (int i = threadIdx.x; i < NN; i += 1024)
        out[(size_t)b * NN + i] = (int)(keys[i] & 0xffffffffu);
}

extern "C" void kernel_launch(void* const* d_in, const int* in_sizes, int n_in,
                              void* d_out, int out_size, void* d_ws, size_t ws_size,
                              hipStream_t stream) {
    const float* X = (const float*)d_in[0];    // [4,8192,3] f32
    const int* C = (const int*)d_in[1];        // [4,8192] int32
    const float* prio = (const float*)d_in[2]; // [4,8192] f32
    int* out = (int*)d_out;                    // [4,8192] i32

    float* z0 = (float*)d_ws;
    float* z1 = z0 + TOT;
    int* edgesT = (int*)(z1 + TOT);            // [KNB][TOT]
    float* Xs = (float*)(edgesT + (size_t)TOT * KNB);  // [NB][3][NN]

    prep_kernel<<<TOT / 256, 256, 0, stream>>>(X, C, z0, Xs);
    knn_kernel<<<TOT, 256, 0, stream>>>(Xs, X, edgesT);

    float* cur = z0;
    float* nxt = z1;
    for (int s = 0; s < 5; ++s) {
        smooth_kernel<<<TOT / 256, 256, 0, stream>>>(cur, nxt, edgesT, C);
        float* tmp = cur; cur = nxt; nxt = tmp;
    }
    sort_kernel<<<NB, 1024, 0, stream>>>(cur, prio, out);
}